// Round 8
// baseline (731.930 us; speedup 1.0000x reference)
//
#include <hip/hip_runtime.h>
#include <cmath>

#define S 512
#define B 256
#define IN 64
#define H 256
#define RPB 16            // batch rows per block in the recurrent kernel
#define HR 264            // h_lds row stride in f16 (528B, 16B-aligned, even banks)

typedef float v4f __attribute__((ext_vector_type(4)));
typedef _Float16 f16x8 __attribute__((ext_vector_type(8)));

// ---------------------------------------------------------------------------
// Kernel 1: xp[s,b,:] = x[s,b,:] @ Wx^T   (written into out[s,b,:], f32)
// Flattened p = s*B + b: x is contiguous at p*64, out at p*256.
// 2048 blocks x 256 threads, 64 (s,b) pairs per block. Wx row j lives in
// 64 VGPRs per thread; x loads are wave-uniform (L1 broadcast).
// ---------------------------------------------------------------------------
__global__ __launch_bounds__(256) void rnn_xproj(
    const float* __restrict__ x, const float* __restrict__ Wx,
    float* __restrict__ out)
{
    const int j = threadIdx.x;
    float w[IN];
    #pragma unroll
    for (int q = 0; q < IN / 4; ++q)
        *(v4f*)&w[4 * q] = *(const v4f*)(Wx + (size_t)j * IN + 4 * q);

    const float* xb = x + (size_t)blockIdx.x * 64 * IN;
    float* ob = out + (size_t)blockIdx.x * 64 * H;

    for (int it = 0; it < 64; ++it) {
        const v4f* xs = (const v4f*)(xb + it * IN);
        float a0 = 0.f, a1 = 0.f, a2 = 0.f, a3 = 0.f;
        #pragma unroll
        for (int q = 0; q < 16; ++q) {
            const v4f xv = xs[q];
            a0 = fmaf(w[4 * q + 0], xv.x, a0);
            a1 = fmaf(w[4 * q + 1], xv.y, a1);
            a2 = fmaf(w[4 * q + 2], xv.z, a2);
            a3 = fmaf(w[4 * q + 3], xv.w, a3);
        }
        ob[it * H + j] = (a0 + a1) + (a2 + a3);
    }
}

// ---------------------------------------------------------------------------
// Kernel 2: the recurrence on MFMA. 16 blocks x 256 threads (4 waves).
// Block owns batch rows [16*blockIdx, +16). Per step: D[16m x 256j] =
// h[16 x 256] @ Wh^T via mfma_f32_16x16x32_f16. Wave w owns j in
// [64w, 64w+64) (4 n-tiles); its B-fragments (Wh^T, f16) are loop-invariant
// in 128 VGPRs. h lives in LDS f16 [2][16][264] (double-buffered);
// A-fragments are 8 ds_read_b128 per wave per step. Epilogue per lane:
// 16 values -> +xp +bias -> tanh -> f16 h_lds write + f32 out store.
// xp is prefetched one step ahead from out[] (written by kernel 1);
// out[t] is overwritten with h(t) only after xp[t] was consumed.
// Barriers are raw s_barrier + lgkmcnt(0): global stores drain in the
// background instead of serializing each step.
// ---------------------------------------------------------------------------
#define BAR() asm volatile("s_waitcnt lgkmcnt(0)\n\ts_barrier" ::: "memory")

__global__ __launch_bounds__(256) void rnn_rec16(
    const float* __restrict__ Wh, const float* __restrict__ bh,
    const float* __restrict__ bx, float* __restrict__ out)
{
    __shared__ __align__(16) _Float16 h_lds[2][RPB][HR];

    const int tid = threadIdx.x;
    const int l   = tid & 63;
    const int wv  = tid >> 6;        // wave 0..3
    const int lo  = l & 15;
    const int hi  = l >> 4;          // 0..3
    const int b0  = blockIdx.x * RPB;

    // ---- B-fragments: B[k][n] = Wh[n][k], f16, loop-invariant ----
    f16x8 bf[4][8];                  // [n-tile][k-tile]
    float bias[4];
    #pragma unroll
    for (int nt = 0; nt < 4; ++nt) {
        const int j = 64 * wv + 16 * nt + lo;
        #pragma unroll
        for (int kt = 0; kt < 8; ++kt) {
            const int k0 = 32 * kt + 8 * hi;
            const v4f p = *(const v4f*)(Wh + (size_t)j * H + k0);
            const v4f q = *(const v4f*)(Wh + (size_t)j * H + k0 + 4);
            bf[nt][kt] = f16x8{(_Float16)p.x, (_Float16)p.y, (_Float16)p.z,
                               (_Float16)p.w, (_Float16)q.x, (_Float16)q.y,
                               (_Float16)q.z, (_Float16)q.w};
        }
        bias[nt] = bh[j] + bx[j];
    }

    // ---- h(0) = 0 ----
    for (int i = tid; i < RPB * HR; i += 256)
        ((_Float16*)h_lds[0])[i] = (_Float16)0.f;

    // xp/out addressing: lane handles (m = 4*hi + r, j = 64*wv + 16*nt + lo)
    const size_t base = (size_t)(b0 + 4 * hi) * H + 64 * wv + lo;

    // ---- prefetch xp(0) ----
    float xpA[4][4], xpB[4][4];
    #pragma unroll
    for (int nt = 0; nt < 4; ++nt)
        #pragma unroll
        for (int r = 0; r < 4; ++r)
            xpA[nt][r] = out[base + (size_t)r * H + 16 * nt];

    __syncthreads();

#define STEP(CUR, NXT, T, XPC, XPN)                                           \
    {                                                                         \
        /* A-fragments: h_lds[CUR], lane: row lo, k = 32*kt + 8*hi .. +8 */   \
        f16x8 af[8];                                                          \
        _Pragma("unroll")                                                     \
        for (int kt = 0; kt < 8; ++kt)                                        \
            af[kt] = *(const f16x8*)&h_lds[CUR][lo][32 * kt + 8 * hi];        \
        /* prefetch xp(T+1) (reads out[] one step ahead of the h-write) */    \
        _Pragma("unroll")                                                     \
        for (int nt = 0; nt < 4; ++nt)                                        \
            _Pragma("unroll")                                                 \
            for (int r = 0; r < 4; ++r)                                       \
                XPN[nt][r] = out[(size_t)((T) + 1) * (B * H) + base +         \
                                 (size_t)r * H + 16 * nt];                    \
        v4f acc[4];                                                           \
        _Pragma("unroll")                                                     \
        for (int nt = 0; nt < 4; ++nt) acc[nt] = v4f{0.f, 0.f, 0.f, 0.f};     \
        _Pragma("unroll")                                                     \
        for (int kt = 0; kt < 8; ++kt) {                                      \
            _Pragma("unroll")                                                 \
            for (int nt = 0; nt < 4; ++nt)                                    \
                acc[nt] = __builtin_amdgcn_mfma_f32_16x16x32_f16(             \
                    af[kt], bf[nt][kt], acc[nt], 0, 0, 0);                    \
        }                                                                     \
        /* epilogue: D + xp + bias -> tanh -> h_lds[NXT] + out[T] */          \
        _Pragma("unroll")                                                     \
        for (int nt = 0; nt < 4; ++nt) {                                      \
            _Pragma("unroll")                                                 \
            for (int r = 0; r < 4; ++r) {                                     \
                const float sum = acc[nt][r] + XPC[nt][r] + bias[nt];         \
                const float pre = fminf(fmaxf(sum, -15.f), 15.f);             \
                const float e = __builtin_amdgcn_exp2f(pre * 2.88539008f);    \
                const float hv = (e - 1.f) * __builtin_amdgcn_rcpf(e + 1.f);  \
                h_lds[NXT][4 * hi + r][64 * wv + 16 * nt + lo] = (_Float16)hv;\
                out[(size_t)(T) * (B * H) + base + (size_t)r * H + 16 * nt] = \
                    hv;                                                       \
            }                                                                 \
        }                                                                     \
        BAR();                                                                \
    }

    for (int t2 = 0; t2 < S / 2; ++t2) {
        STEP(0, 1, 2 * t2,     xpA, xpB);
        STEP(1, 0, 2 * t2 + 1, xpB, xpA);
    }
#undef STEP

    // ---- last h: final state sits in h_lds[0]; each lane re-stores its own ----
    #pragma unroll
    for (int nt = 0; nt < 4; ++nt)
        #pragma unroll
        for (int r = 0; r < 4; ++r)
            out[(size_t)S * B * H + base + (size_t)r * H + 16 * nt] =
                (float)h_lds[0][4 * hi + r][64 * wv + 16 * nt + lo];
}

extern "C" void kernel_launch(void* const* d_in, const int* in_sizes, int n_in,
                              void* d_out, int out_size, void* d_ws, size_t ws_size,
                              hipStream_t stream) {
    const float* x  = (const float*)d_in[0];
    const float* Wx = (const float*)d_in[1];
    const float* bx = (const float*)d_in[2];
    const float* Wh = (const float*)d_in[3];
    const float* bh = (const float*)d_in[4];
    float* out = (float*)d_out;

    rnn_xproj<<<dim3(2048), dim3(256), 0, stream>>>(x, Wx, out);
    rnn_rec16<<<dim3(B / RPB), dim3(256), 0, stream>>>(Wh, bh, bx, out);
}

// Round 9
// 584.946 us; speedup vs baseline: 1.2513x; 1.2513x over previous
//
#include <hip/hip_runtime.h>
#include <cmath>

#define S 512
#define B 256
#define IN 64
#define H 256
#define RPB 16            // batch rows per block in the recurrent kernel
#define HR 264            // h_lds row stride in f16 (528B, 16B-aligned)

typedef float v4f __attribute__((ext_vector_type(4)));
typedef _Float16 f16x8 __attribute__((ext_vector_type(8)));

// ---------------------------------------------------------------------------
// Kernel 1: xp[s,b,:] = x[s,b,:] @ Wx^T  (written into out[s,b,:], f32)
// 2048 blocks x 256 threads, 64 (s,b) pairs per block. The x-tile (16 KB)
// is staged in LDS once (coalesced cooperative load); inner reads are
// wave-uniform ds_read_b128 broadcasts (free, ~25cy) instead of global
// loads -- the round-8 version was latency-bound on its 16 uniform
// global loads per iteration (~145us vs ~30us floor).
// ---------------------------------------------------------------------------
__global__ __launch_bounds__(256) void rnn_xproj2(
    const float* __restrict__ x, const float* __restrict__ Wx,
    float* __restrict__ out)
{
    __shared__ __align__(16) float xt[64 * IN];    // 16 KB
    const int j = threadIdx.x;

    float w[IN];
    #pragma unroll
    for (int q = 0; q < IN / 4; ++q)
        *(v4f*)&w[4 * q] = *(const v4f*)(Wx + (size_t)j * IN + 4 * q);

    const v4f* src = (const v4f*)(x + (size_t)blockIdx.x * 64 * IN);
    #pragma unroll
    for (int q = 0; q < 4; ++q)
        ((v4f*)xt)[j + 256 * q] = src[j + 256 * q];
    __syncthreads();

    float* ob = out + (size_t)blockIdx.x * 64 * H + j;
    #pragma unroll 2
    for (int it = 0; it < 64; ++it) {
        const v4f* xs = (const v4f*)(xt + it * IN);
        float a0 = 0.f, a1 = 0.f, a2 = 0.f, a3 = 0.f;
        #pragma unroll
        for (int q = 0; q < 16; ++q) {
            const v4f xv = xs[q];
            a0 = fmaf(w[4 * q + 0], xv.x, a0);
            a1 = fmaf(w[4 * q + 1], xv.y, a1);
            a2 = fmaf(w[4 * q + 2], xv.z, a2);
            a3 = fmaf(w[4 * q + 3], xv.w, a3);
        }
        ob[it * H] = (a0 + a1) + (a2 + a3);
    }
}

// ---------------------------------------------------------------------------
// Kernel 2: recurrence on MFMA. 16 blocks x 512 threads (8 waves, 2/SIMD).
// Round-8 ran 1 wave/SIMD and was latency-bound (per-active-CU MfmaUtil
// ~22%, VALUBusy ~44%): every ds_read / MFMA-chain / transcendental /
// barrier latency was exposed. 2 waves/SIMD lets one wave issue while
// the other stalls. Wave wv owns cols [32wv,+32) (2 n-tiles, B-frags =
// 64 VGPR loop-invariant); per lane epilogue = 8 outputs. Same verified
// MFMA layout / xp-through-out[] scheme as round 8.
// ---------------------------------------------------------------------------
#define BAR() asm volatile("s_waitcnt lgkmcnt(0)\n\ts_barrier" ::: "memory")

__global__ __launch_bounds__(512, 2) void rnn_rec16b(
    const float* __restrict__ Wh, const float* __restrict__ bh,
    const float* __restrict__ bx, float* __restrict__ out)
{
    __shared__ __align__(16) _Float16 h_lds[2][RPB][HR];

    const int tid = threadIdx.x;
    const int l   = tid & 63;
    const int wv  = tid >> 6;        // wave 0..7
    const int lo  = l & 15;
    const int hi  = l >> 4;          // 0..3
    const int b0  = blockIdx.x * RPB;

    // ---- B-fragments: B[k][n] = Wh[n][k], f16, loop-invariant ----
    f16x8 bf[2][8];                  // [n-tile][k-tile]
    float bias[2];
    #pragma unroll
    for (int nt = 0; nt < 2; ++nt) {
        const int j = 32 * wv + 16 * nt + lo;
        #pragma unroll
        for (int kt = 0; kt < 8; ++kt) {
            const int k0 = 32 * kt + 8 * hi;
            const v4f p = *(const v4f*)(Wh + (size_t)j * H + k0);
            const v4f q = *(const v4f*)(Wh + (size_t)j * H + k0 + 4);
            bf[nt][kt] = f16x8{(_Float16)p.x, (_Float16)p.y, (_Float16)p.z,
                               (_Float16)p.w, (_Float16)q.x, (_Float16)q.y,
                               (_Float16)q.z, (_Float16)q.w};
        }
        bias[nt] = bh[j] + bx[j];
    }

    // ---- h(0) = 0 ----
    for (int i = tid; i < RPB * HR; i += 512)
        ((_Float16*)h_lds[0])[i] = (_Float16)0.f;

    // lane handles (m = 4*hi + r, col = 32*wv + 16*nt + lo)
    const size_t base = (size_t)(b0 + 4 * hi) * H + 32 * wv + lo;

    // ---- prefetch xp(0) ----
    float xpA[2][4], xpB[2][4];
    #pragma unroll
    for (int nt = 0; nt < 2; ++nt)
        #pragma unroll
        for (int r = 0; r < 4; ++r)
            xpA[nt][r] = out[base + (size_t)r * H + 16 * nt];

    __syncthreads();

#define STEP(CUR, NXT, T, XPC, XPN)                                           \
    {                                                                         \
        /* A-fragments: row lo, k = 32*kt + 8*hi .. +8 */                     \
        f16x8 af[8];                                                          \
        _Pragma("unroll")                                                     \
        for (int kt = 0; kt < 8; ++kt)                                        \
            af[kt] = *(const f16x8*)&h_lds[CUR][lo][32 * kt + 8 * hi];        \
        /* prefetch xp(T+1): one full step of slack before use */             \
        _Pragma("unroll")                                                     \
        for (int nt = 0; nt < 2; ++nt)                                        \
            _Pragma("unroll")                                                 \
            for (int r = 0; r < 4; ++r)                                       \
                XPN[nt][r] = out[(size_t)((T) + 1) * (B * H) + base +         \
                                 (size_t)r * H + 16 * nt];                    \
        v4f acc[2];                                                           \
        _Pragma("unroll")                                                     \
        for (int nt = 0; nt < 2; ++nt) acc[nt] = v4f{0.f, 0.f, 0.f, 0.f};     \
        _Pragma("unroll")                                                     \
        for (int nt = 0; nt < 2; ++nt) {                                      \
            _Pragma("unroll")                                                 \
            for (int kt = 0; kt < 8; ++kt)                                    \
                acc[nt] = __builtin_amdgcn_mfma_f32_16x16x32_f16(             \
                    af[kt], bf[nt][kt], acc[nt], 0, 0, 0);                    \
        }                                                                     \
        /* epilogue: D + xp + bias -> tanh -> h_lds[NXT] + out[T] */          \
        _Pragma("unroll")                                                     \
        for (int nt = 0; nt < 2; ++nt) {                                      \
            _Pragma("unroll")                                                 \
            for (int r = 0; r < 4; ++r) {                                     \
                const float sum = acc[nt][r] + XPC[nt][r] + bias[nt];         \
                const float pre = __builtin_amdgcn_fmed3f(sum, -15.f, 15.f);  \
                const float e = __builtin_amdgcn_exp2f(pre * 2.88539008f);    \
                const float hv = (e - 1.f) * __builtin_amdgcn_rcpf(e + 1.f);  \
                h_lds[NXT][4 * hi + r][32 * wv + 16 * nt + lo] = (_Float16)hv;\
                out[(size_t)(T) * (B * H) + base + (size_t)r * H + 16 * nt] = \
                    hv;                                                       \
            }                                                                 \
        }                                                                     \
        BAR();                                                                \
    }

    for (int t2 = 0; t2 < S / 2; ++t2) {
        STEP(0, 1, 2 * t2,     xpA, xpB);
        STEP(1, 0, 2 * t2 + 1, xpB, xpA);
    }
#undef STEP

    // ---- last h: final state sits in h_lds[0] ----
    #pragma unroll
    for (int nt = 0; nt < 2; ++nt)
        #pragma unroll
        for (int r = 0; r < 4; ++r)
            out[(size_t)S * B * H + base + (size_t)r * H + 16 * nt] =
                (float)h_lds[0][4 * hi + r][32 * wv + 16 * nt + lo];
}

extern "C" void kernel_launch(void* const* d_in, const int* in_sizes, int n_in,
                              void* d_out, int out_size, void* d_ws, size_t ws_size,
                              hipStream_t stream) {
    const float* x  = (const float*)d_in[0];
    const float* Wx = (const float*)d_in[1];
    const float* bx = (const float*)d_in[2];
    const float* Wh = (const float*)d_in[3];
    const float* bh = (const float*)d_in[4];
    float* out = (float*)d_out;

    rnn_xproj2<<<dim3(2048), dim3(256), 0, stream>>>(x, Wx, out);
    rnn_rec16b<<<dim3(B / RPB), dim3(512), 0, stream>>>(Wh, bh, bx, out);
}

// Round 10
// 406.387 us; speedup vs baseline: 1.8011x; 1.4394x over previous
//
#include <hip/hip_runtime.h>
#include <cmath>

#define S 512
#define B 256
#define IN 64
#define H 256
#define KT 10                 // k-tiles: 8 over h (256) + 2 over x (64)
#define KW 320                // concat row: h[0..256) ++ x[256..320), f16

typedef float v4f __attribute__((ext_vector_type(4)));
typedef __fp16 h2 __attribute__((ext_vector_type(2)));
typedef _Float16 f16x8 __attribute__((ext_vector_type(8)));

// ---------------------------------------------------------------------------
// Single fused kernel: 256 blocks (one batch row each) x 512 threads
// (8 waves, 2/SIMD). The recurrence runs on MFMA with a REPLICATED-A
// trick: all 16 A-rows of mfma_f32_16x16x32_f16 hold the SAME h-row, so
// the A-fragment load is a 4-distinct-address LDS broadcast (4 adjacent
// 16B lines -> disjoint banks -> conflict-free, ~5cy) instead of a 1KB
// fragment read; D comes out row-replicated and lanes hi==0 read row 0.
// x is folded into the same GEMM by k-concat [h | x] with W' = [Wh | Wx]
// (10 k-tiles) -- no separate x-projection kernel, no xp global traffic
// (round 9 was per-CU-HBM-bound moving 198 MB through 16 CUs; here the
// 131 MB of h-stores spread over 256 CUs). Fragment mappings identical
// to the round-8/9-verified kernels (passed absmax 0.0039):
//   B-frag: lane l -> col j = 32wv+16nt+(l&15), k = 32kt+8(l>>4)..+8
//   A-frag: lane l -> row l&15 (replicated), same k-slice
//   C/D:    lane l -> col l&15, row 4(l>>4)+r  (row 0 = hi==0, r==0)
// Barrier is raw s_barrier + lgkmcnt(0): out[] stores drain in the
// background (vmcnt never forced to 0 inside the loop).
// ---------------------------------------------------------------------------
#define BAR() asm volatile("s_waitcnt lgkmcnt(0)\n\ts_barrier" ::: "memory")

__global__ __launch_bounds__(512, 2) void rnn_mfma1(
    const float* __restrict__ x,   // [S,B,IN]
    const float* __restrict__ Wx,  // [H,IN]
    const float* __restrict__ bx,  // [H]
    const float* __restrict__ Wh,  // [H,H]
    const float* __restrict__ bh,  // [H]
    float* __restrict__ out)       // [S,B,H] ++ [1,B,H]
{
    __shared__ __align__(16) __fp16 hx[2][KW];   // double-buffered [h|x] row

    const int tid = threadIdx.x;
    const int l   = tid & 63;
    const int wv  = tid >> 6;      // wave 0..7: owns cols [32wv, 32wv+32)
    const int lo  = l & 15;
    const int hi  = l >> 4;        // 0..3
    const int b   = blockIdx.x;

    // ---- B-fragments (loop-invariant, 80 VGPR): B[k][j] = W'[j][k] ----
    f16x8 bf[2][KT];
    float bias[2];
    #pragma unroll
    for (int nt = 0; nt < 2; ++nt) {
        const int j = 32 * wv + 16 * nt + lo;
        #pragma unroll
        for (int kt = 0; kt < 8; ++kt) {         // h-part: Wh[j][32kt+8hi..]
            const int k0 = 32 * kt + 8 * hi;
            const v4f p = *(const v4f*)(Wh + (size_t)j * H + k0);
            const v4f q = *(const v4f*)(Wh + (size_t)j * H + k0 + 4);
            bf[nt][kt] = f16x8{(_Float16)p.x, (_Float16)p.y, (_Float16)p.z,
                               (_Float16)p.w, (_Float16)q.x, (_Float16)q.y,
                               (_Float16)q.z, (_Float16)q.w};
        }
        #pragma unroll
        for (int kt = 8; kt < KT; ++kt) {        // x-part: Wx[j][32(kt-8)+8hi..]
            const int k0 = 32 * (kt - 8) + 8 * hi;
            const v4f p = *(const v4f*)(Wx + (size_t)j * IN + k0);
            const v4f q = *(const v4f*)(Wx + (size_t)j * IN + k0 + 4);
            bf[nt][kt] = f16x8{(_Float16)p.x, (_Float16)p.y, (_Float16)p.z,
                               (_Float16)p.w, (_Float16)q.x, (_Float16)q.y,
                               (_Float16)q.z, (_Float16)q.w};
        }
        bias[nt] = bh[j] + bx[j];
    }

    // ---- init: h(0)=0, stage x(0) (disjoint regions, one barrier) ----
    if (tid < H) hx[0][tid] = (__fp16)0.f;
    if (tid < 16) {
        const v4f x0 = *(const v4f*)(x + (size_t)b * IN + 4 * tid);
        *(h2*)&hx[0][H + 4 * tid]     = __builtin_amdgcn_cvt_pkrtz(x0.x, x0.y);
        *(h2*)&hx[0][H + 4 * tid + 2] = __builtin_amdgcn_cvt_pkrtz(x0.z, x0.w);
    }
    __syncthreads();

#define STEP(CUR, NXT, T)                                                     \
    {                                                                         \
        /* A-fragments: 4-line broadcast reads, replicated across rows */     \
        f16x8 af[KT];                                                         \
        _Pragma("unroll")                                                     \
        for (int kt = 0; kt < KT; ++kt)                                       \
            af[kt] = *(const f16x8*)&hx[CUR][32 * kt + 8 * hi];               \
        /* prefetch x(T+1), coalesced 256B; latency hides under MFMA */       \
        v4f xn;                                                               \
        const bool pf = (tid < 16) && ((T) + 1 < S);                          \
        if (pf) xn = *(const v4f*)(x + (size_t)((T) + 1) * (B * IN) +         \
                                   (size_t)b * IN + 4 * tid);                 \
        v4f acc0 = {0.f, 0.f, 0.f, 0.f}, acc1 = {0.f, 0.f, 0.f, 0.f};         \
        _Pragma("unroll")                                                     \
        for (int kt = 0; kt < KT; ++kt) {                                     \
            acc0 = __builtin_amdgcn_mfma_f32_16x16x32_f16(af[kt], bf[0][kt],  \
                                                          acc0, 0, 0, 0);     \
            acc1 = __builtin_amdgcn_mfma_f32_16x16x32_f16(af[kt], bf[1][kt],  \
                                                          acc1, 0, 0, 0);     \
        }                                                                     \
        /* epilogue: rows replicated -> lanes hi==0 own cols 32wv+16nt+lo */  \
        if (hi == 0) {                                                        \
            _Pragma("unroll")                                                 \
            for (int nt = 0; nt < 2; ++nt) {                                  \
                const float sum = (nt ? acc1[0] : acc0[0]) + bias[nt];        \
                const float pre = __builtin_amdgcn_fmed3f(sum, -15.f, 15.f);  \
                const float e  = __builtin_amdgcn_exp2f(pre * 2.88539008f);   \
                const float hv = (e - 1.f) * __builtin_amdgcn_rcpf(e + 1.f);  \
                hx[NXT][32 * wv + 16 * nt + lo] = (__fp16)hv;                 \
                out[(size_t)(T) * (B * H) + (size_t)b * H +                   \
                    32 * wv + 16 * nt + lo] = hv;                             \
            }                                                                 \
        }                                                                     \
        if (pf) {                                                             \
            *(h2*)&hx[NXT][H + 4 * tid]     =                                 \
                __builtin_amdgcn_cvt_pkrtz(xn.x, xn.y);                       \
            *(h2*)&hx[NXT][H + 4 * tid + 2] =                                 \
                __builtin_amdgcn_cvt_pkrtz(xn.z, xn.w);                       \
        }                                                                     \
        BAR();                                                                \
    }

    for (int t2 = 0; t2 < S / 2; ++t2) {
        STEP(0, 1, 2 * t2);
        STEP(1, 0, 2 * t2 + 1);
    }
#undef STEP

    // ---- last h: h(S) sits in hx[0][0..256) ----
    if (tid < H)
        out[(size_t)S * B * H + (size_t)b * H + tid] = (float)hx[0][tid];
}

extern "C" void kernel_launch(void* const* d_in, const int* in_sizes, int n_in,
                              void* d_out, int out_size, void* d_ws, size_t ws_size,
                              hipStream_t stream) {
    const float* x  = (const float*)d_in[0];
    const float* Wx = (const float*)d_in[1];
    const float* bx = (const float*)d_in[2];
    const float* Wh = (const float*)d_in[3];
    const float* bh = (const float*)d_in[4];
    float* out = (float*)d_out;

    rnn_mfma1<<<dim3(B), dim3(512), 0, stream>>>(x, Wx, bx, Wh, bh, out);
}